// Round 11
// baseline (246.884 us; speedup 1.0000x reference)
//
#include <hip/hip_runtime.h>

// CRF log-partition forward, MI355X. 64 blocks (1 per sequence) x 128 threads
// (2 waves, pinned 1 wave/EU). Round-11: cut LDS BROADCAST RETURN traffic.
// Deliveries = 128i x 128j / j_lane floats per step; round 10 (j_lane=2) paid
// 32 KB/step (~380 cyc of LDS pipe). Here j_lane=8: 8 KB/step.
// Tile: k = tid&7 -> i-chunk [16k,16k+16), g = tid>>3 -> tags [8g,8g+8) as
// 4 f2 column-pairs. 64 pk-FMA/lane/step (4 chains, depth 16).
// Combine: DPP quad butterfly (xor1,xor2) -> select column-pair (lanes k and
// k^4 pick the same pair k&3) -> ONE f2 ds_swizzle xor4. Writers k<4 store
// their tag pair as ds_write_b64.
//
// E tile: 64 NAMED f2 registers (128 VGPRs) + amdgpu_waves_per_eu(1,1) so the
// allocator keeps E in arch VGPRs (rounds 5-9 lesson: default occupancy
// heuristic parks it in AGPRs and pays v_accvgpr copies every step).
// Barrier: lgkmcnt-only inline asm (cross-wave data is LDS-only) so the
// distance-4 emission prefetch stays in flight across steps.
//
// Linear-domain recurrence with exact power-of-2 renormalization:
//   q'_j = exp2(e_j*log2e) * (sum_i q_i E_ij) * 2^(-eS),  eS = exponent(q_0)
//   o    += eS   (integer, exact)
// alpha_j = ln2 * (o + log2 q_j). Final: ln2*(o + log2 sum_j q_j*exp(end_j)).

#define LOG2E 1.4426950408889634f
#define LN2   0.6931471805599453f

// LDS-only workgroup barrier: no vmcnt drain (cross-wave data is LDS only).
#define LDS_BARRIER() asm volatile("s_waitcnt lgkmcnt(0)\n\ts_barrier" ::: "memory")

typedef float f2 __attribute__((ext_vector_type(2)));

template <int CTRL>
__device__ __forceinline__ float dpp_f(float x) {
    return __int_as_float(
        __builtin_amdgcn_mov_dpp(__float_as_int(x), CTRL, 0xF, 0xF, false));
}
template <int CTRL>
__device__ __forceinline__ f2 dpp_f2(f2 x) {
    f2 r;
    r.x = dpp_f<CTRL>(x.x);
    r.y = dpp_f<CTRL>(x.y);
    return r;
}
// quad_perm codes: xor1 = 0xB1, xor2 = 0x4E
__device__ __forceinline__ float swz_xor4(float x) {
    // BitMode: offset = (xor<<10)|(or<<5)|and ; xor=4, and=0x1F
    return __int_as_float(
        __builtin_amdgcn_ds_swizzle(__float_as_int(x), (4 << 10) | 0x1F));
}

__global__ __launch_bounds__(128)
__attribute__((amdgpu_waves_per_eu(1, 1)))
void crf_forward(
    const float* __restrict__ emissions,   // [64, 512, 128]
    const float* __restrict__ transitions, // [128, 128]
    const float* __restrict__ start_t,     // [128]
    const float* __restrict__ end_t,       // [128]
    const int*   __restrict__ lengths,     // [64]
    float* __restrict__ out)               // [64]
{
    constexpr int N = 128;
    constexpr int L = 512;
    constexpr int PW = 20;   // 16 floats + 4 pad per chunk (80 B, 16B-aligned)
    const int b   = blockIdx.x;
    const int tid = threadIdx.x;
    const int g   = tid >> 3;            // j-octet: tags [8g, 8g+8)
    const int k   = tid & 7;             // i-chunk: i in [16k, 16k+16)
    const int jp  = 8 * g + 2 * (k & 3); // this lane's tag pair (writer iff k<4)

    // tag j at word (j>>4)*PW + (j&15); 8 chunk bases {0,20,40,..,140} mod 32
    // are pairwise-distinct and their b128 spans cover all 32 banks once.
    __shared__ alignas(16) float pbuf[2][8 * PW];
    __shared__ float wsum[2];

    // ---- one-time: 16i x 8j E tile as 64 NAMED f2 registers (128 VGPRs).
    // Ea=cols{0,1}, Eb={2,3}, Ec={4,5}, Ed={6,7} relative to 8g.
    f2 Ea_0, Ea_1, Ea_2,  Ea_3,  Ea_4,  Ea_5,  Ea_6,  Ea_7;
    f2 Ea_8, Ea_9, Ea_10, Ea_11, Ea_12, Ea_13, Ea_14, Ea_15;
    f2 Eb_0, Eb_1, Eb_2,  Eb_3,  Eb_4,  Eb_5,  Eb_6,  Eb_7;
    f2 Eb_8, Eb_9, Eb_10, Eb_11, Eb_12, Eb_13, Eb_14, Eb_15;
    f2 Ec_0, Ec_1, Ec_2,  Ec_3,  Ec_4,  Ec_5,  Ec_6,  Ec_7;
    f2 Ec_8, Ec_9, Ec_10, Ec_11, Ec_12, Ec_13, Ec_14, Ec_15;
    f2 Ed_0, Ed_1, Ed_2,  Ed_3,  Ed_4,  Ed_5,  Ed_6,  Ed_7;
    f2 Ed_8, Ed_9, Ed_10, Ed_11, Ed_12, Ed_13, Ed_14, Ed_15;
    {
        const float* tb = transitions + (size_t)(16 * k) * N + 8 * g;
#define INIT_E(ii)                                                             \
        {                                                                      \
            float4 t0 = *reinterpret_cast<const float4*>(tb + (size_t)(ii) * N);     \
            float4 t1 = *reinterpret_cast<const float4*>(tb + (size_t)(ii) * N + 4); \
            Ea_##ii.x = __builtin_amdgcn_exp2f(t0.x * LOG2E);                  \
            Ea_##ii.y = __builtin_amdgcn_exp2f(t0.y * LOG2E);                  \
            Eb_##ii.x = __builtin_amdgcn_exp2f(t0.z * LOG2E);                  \
            Eb_##ii.y = __builtin_amdgcn_exp2f(t0.w * LOG2E);                  \
            Ec_##ii.x = __builtin_amdgcn_exp2f(t1.x * LOG2E);                  \
            Ec_##ii.y = __builtin_amdgcn_exp2f(t1.y * LOG2E);                  \
            Ed_##ii.x = __builtin_amdgcn_exp2f(t1.z * LOG2E);                  \
            Ed_##ii.y = __builtin_amdgcn_exp2f(t1.w * LOG2E);                  \
        }
        INIT_E(0)  INIT_E(1)  INIT_E(2)  INIT_E(3)
        INIT_E(4)  INIT_E(5)  INIT_E(6)  INIT_E(7)
        INIT_E(8)  INIT_E(9)  INIT_E(10) INIT_E(11)
        INIT_E(12) INIT_E(13) INIT_E(14) INIT_E(15)
#undef INIT_E
    }

    const int len = lengths[b];
    const float* eb = emissions + (size_t)b * L * N;

    // ---- init: q_j = exp2((start_j + e0_j)*log2e), tid == tag
    {
        float q = __builtin_amdgcn_exp2f((start_t[tid] + eb[tid]) * LOG2E);
        pbuf[0][(tid >> 4) * PW + (tid & 15)] = q;
    }
    int o = 0;
    int cur = 0;
    LDS_BARRIER();

    auto clampt = [&](int tt) { return tt < len ? tt : len - 1; };
    auto ldE = [&](int tt) {
        return *reinterpret_cast<const f2*>(eb + (size_t)tt * N + jp);
    };

    auto STEP = [&](f2 e_cur) {
        // normalizer source (b32 broadcast) + my 16-float chunk (4x b128;
        // 8 chunk bases cover all 32 banks exactly once -> conflict-free)
        float p0 = pbuf[cur][0];
        const float4* pv = reinterpret_cast<const float4*>(&pbuf[cur][k * PW]);
        float4 v0 = pv[0], v1 = pv[1], v2 = pv[2], v3 = pv[3];

        int eS = (int)((__float_as_uint(p0) >> 23) & 0xFFu) - 127;
        o += eS;
        float scale = __uint_as_float((unsigned)(127 - eS) << 23);
        f2 es;
        es.x = __builtin_amdgcn_exp2f(e_cur.x * LOG2E) * scale;
        es.y = __builtin_amdgcn_exp2f(e_cur.y * LOG2E) * scale;

        // 64 pk-FMA over the 16i x 8j tile, 4 chains (one per column pair)
        f2 aa = {0.f, 0.f}, ab = {0.f, 0.f}, ac = {0.f, 0.f}, ad = {0.f, 0.f};
#define ACC(vc, ii)                                                            \
        {                                                                      \
            f2 pp = {vc, vc};                                                  \
            aa = __builtin_elementwise_fma(pp, Ea_##ii, aa);                   \
            ab = __builtin_elementwise_fma(pp, Eb_##ii, ab);                   \
            ac = __builtin_elementwise_fma(pp, Ec_##ii, ac);                   \
            ad = __builtin_elementwise_fma(pp, Ed_##ii, ad);                   \
        }
        ACC(v0.x, 0)  ACC(v0.y, 1)  ACC(v0.z, 2)  ACC(v0.w, 3)
        ACC(v1.x, 4)  ACC(v1.y, 5)  ACC(v1.z, 6)  ACC(v1.w, 7)
        ACC(v2.x, 8)  ACC(v2.y, 9)  ACC(v2.z, 10) ACC(v2.w, 11)
        ACC(v3.x, 12) ACC(v3.y, 13) ACC(v3.z, 14) ACC(v3.w, 15)
#undef ACC

        // quad butterfly (DPP): each quad lane now has its quad's partial
        // (i over 64 tags) of all 4 column pairs
        aa += dpp_f2<0xB1>(aa); ab += dpp_f2<0xB1>(ab);
        ac += dpp_f2<0xB1>(ac); ad += dpp_f2<0xB1>(ad);
        aa += dpp_f2<0x4E>(aa); ab += dpp_f2<0x4E>(ab);
        ac += dpp_f2<0x4E>(ac); ad += dpp_f2<0x4E>(ad);

        // select this lane's column pair (lanes k, k^4 pick the same pair),
        // then ONE f2 swizzle-xor4 completes the 8-way i-reduction
        f2 lo = (k & 2) ? ab : aa;
        f2 hi = (k & 2) ? ad : ac;
        f2 dm = (k & 1) ? ((k & 2) ? ad : ac) : lo;   // pair index k&3
        // (k&3)==0 -> aa, 1 -> ab? careful: pair = k&3: 0:aa 1:ab 2:ac 3:ad
        dm = (k & 1) ? ((k & 2) ? ad : ab) : ((k & 2) ? ac : aa);
        (void)lo; (void)hi;
        dm.x += swz_xor4(dm.x);
        dm.y += swz_xor4(dm.y);

        f2 pn = es * dm;
        cur ^= 1;
        if (k < 4) {
            // tag pair jp: word (jp>>4)*PW + (jp&15), b64 store
            *reinterpret_cast<f2*>(&pbuf[cur][(jp >> 4) * PW + (jp & 15)]) = pn;
        }
        LDS_BARRIER();
    };

    // ---- main loop: distance-4 emission prefetch, manual 4-way unroll
    f2 ra = ldE(clampt(1));
    f2 rb = ldE(clampt(2));
    f2 rc = ldE(clampt(3));
    f2 rd = ldE(clampt(4));

    int t = 1;
    while (t < len) {
        STEP(ra); ra = ldE(clampt(t + 4)); ++t; if (t >= len) break;
        STEP(rb); rb = ldE(clampt(t + 4)); ++t; if (t >= len) break;
        STEP(rc); rc = ldE(clampt(t + 4)); ++t; if (t >= len) break;
        STEP(rd); rd = ldE(clampt(t + 4)); ++t;
    }

    // ---- finalize: out[b] = ln2 * (o + log2(sum_j q_j * exp2(end_j*log2e)))
    {
        float q = pbuf[cur][(tid >> 4) * PW + (tid & 15)];
        float vend = q * __builtin_amdgcn_exp2f(end_t[tid] * LOG2E);
        #pragma unroll
        for (int m = 1; m < 64; m <<= 1) vend += __shfl_xor(vend, m);
        if ((tid & 63) == 0) wsum[tid >> 6] = vend;
    }
    LDS_BARRIER();
    if (tid == 0)
        out[b] = LN2 * ((float)o + __builtin_amdgcn_logf(wsum[0] + wsum[1]));
}

extern "C" void kernel_launch(void* const* d_in, const int* in_sizes, int n_in,
                              void* d_out, int out_size, void* d_ws, size_t ws_size,
                              hipStream_t stream) {
    const float* emissions   = (const float*)d_in[0];
    const float* transitions = (const float*)d_in[1];
    const float* start_t     = (const float*)d_in[2];
    const float* end_t       = (const float*)d_in[3];
    const int*   lengths     = (const int*)d_in[4];
    float* out = (float*)d_out;

    crf_forward<<<dim3(64), dim3(128), 0, stream>>>(
        emissions, transitions, start_t, end_t, lengths, out);
}